// Round 1
// baseline (494.869 us; speedup 1.0000x reference)
//
#include <hip/hip_runtime.h>

#define DMODEL 1024
#define NH 16
#define DK 64
#define NB 4
#define SEQ 2048
#define MTOT (NB*SEQ)

typedef __attribute__((ext_vector_type(8))) short bf16x8;
typedef __attribute__((ext_vector_type(4))) float f32x4;
typedef __attribute__((ext_vector_type(4))) float f4;
typedef __attribute__((ext_vector_type(4))) unsigned short us4;
typedef __attribute__((ext_vector_type(8))) unsigned short us8;
typedef const __attribute__((address_space(1))) void* as1cv;
typedef __attribute__((address_space(3))) void* as3v;

__device__ __forceinline__ unsigned short f2bf(float f){
  union { float f; unsigned u; } v; v.f = f;
  unsigned r = v.u + 0x7FFFu + ((v.u >> 16) & 1u);   // RNE
  return (unsigned short)(r >> 16);
}

// ---------------- fp32 -> bf16 convert (weights) ----------------
__global__ __launch_bounds__(256) void cvt_kernel(const float* __restrict__ src,
                                                  unsigned short* __restrict__ dst, int n4){
  int i = blockIdx.x*256 + threadIdx.x;
  if (i >= n4) return;
  f4 f = ((const f4*)src)[i];
  us4 o;
  o.x = f2bf(f.x); o.y = f2bf(f.y); o.z = f2bf(f.z); o.w = f2bf(f.w);
  ((us4*)dst)[i] = o;
}

// ---------------- GEMM: C = A @ B^T + bias ----------------
// A: [M=8192, K=1024] fp32 (AF32=1, reg-staged+converted) or bf16 (AF32=0, global_load_lds)
// B: [N=1024, K=1024] bf16 (torch Linear weight layout)
// MODE 0: dst bf16 in [B,H,S,DK] layout, value = (acc+bias)*scale
// MODE 2: dst fp32 [M, N], value = acc + bias
template<int MODE, int AF32>
__global__ __launch_bounds__(256) void gemm_bt(const void* __restrict__ Aptr,
    const unsigned short* __restrict__ Bw, const float* __restrict__ bias,
    void* __restrict__ dst, float scale)
{
  __shared__ __align__(16) unsigned short sA[128*32];
  __shared__ __align__(16) unsigned short sB[128*32];
  const int tid = threadIdx.x;
  const int lane = tid & 63;
  const int w = tid >> 6;
  const int m0 = blockIdx.y * 128;
  const int n0 = blockIdx.x * 128;
  const int fr = lane & 15;
  const int kg = lane >> 4;
  const int msub = (w & 1) * 64;
  const int nsub = (w >> 1) * 64;

  f32x4 acc[4][4];
#pragma unroll
  for (int i = 0; i < 4; i++)
#pragma unroll
    for (int j = 0; j < 4; j++) acc[i][j] = f32x4{0.f,0.f,0.f,0.f};

  for (int kt = 0; kt < DMODEL; kt += 32){
#pragma unroll
    for (int j = 0; j < 2; j++){
      const int idx = j*256 + tid;
      const int row = idx >> 2;
      const int cg  = (idx & 3) << 3;
      if (AF32){
        const float* ap = (const float*)Aptr + (size_t)(m0+row)*DMODEL + kt + cg;
        f4 f0 = *(const f4*)ap;
        f4 f1 = *(const f4*)(ap + 4);
        us8 o;
        o[0]=f2bf(f0.x); o[1]=f2bf(f0.y); o[2]=f2bf(f0.z); o[3]=f2bf(f0.w);
        o[4]=f2bf(f1.x); o[5]=f2bf(f1.y); o[6]=f2bf(f1.z); o[7]=f2bf(f1.w);
        *((us8*)sA + idx) = o;
      } else {
        const unsigned short* ap = (const unsigned short*)Aptr + (size_t)(m0+row)*DMODEL + kt + cg;
        __builtin_amdgcn_global_load_lds((as1cv)ap, (as3v)(&sA[(size_t)idx*8]), 16, 0, 0);
      }
      const unsigned short* bp = Bw + (size_t)(n0+row)*DMODEL + kt + cg;
      __builtin_amdgcn_global_load_lds((as1cv)bp, (as3v)(&sB[(size_t)idx*8]), 16, 0, 0);
    }
    __syncthreads();
    bf16x8 af[4], bfr[4];
#pragma unroll
    for (int f = 0; f < 4; f++)
      af[f] = *(const bf16x8*)&sA[(msub + f*16 + fr)*32 + kg*8];
#pragma unroll
    for (int f = 0; f < 4; f++)
      bfr[f] = *(const bf16x8*)&sB[(nsub + f*16 + fr)*32 + kg*8];
#pragma unroll
    for (int i = 0; i < 4; i++)
#pragma unroll
      for (int j = 0; j < 4; j++)
        acc[i][j] = __builtin_amdgcn_mfma_f32_16x16x32_bf16(af[i], bfr[j], acc[i][j], 0, 0, 0);
    __syncthreads();
  }

  // epilogue: C/D layout col = lane&15, row = (lane>>4)*4 + r  [m89-verified]
#pragma unroll
  for (int i = 0; i < 4; i++){
#pragma unroll
    for (int j = 0; j < 4; j++){
      const int n = n0 + nsub + j*16 + fr;
      const float bv = bias[n];
#pragma unroll
      for (int r = 0; r < 4; r++){
        const int m = m0 + msub + i*16 + kg*4 + r;
        float vacc = acc[i][j][r] + bv;
        if (MODE == 2){
          ((float*)dst)[(size_t)m*DMODEL + n] = vacc;
        } else {
          const int b = m >> 11, s = m & (SEQ-1);
          const int h = n >> 6,  d = n & (DK-1);
          ((unsigned short*)dst)[((size_t)(b*NH + h)*SEQ + s)*DK + d] = f2bf(vacc * scale);
        }
      }
    }
  }
}

// ---------------- flash attention ----------------
// grid (S/64, B*H), 256 threads = 4 waves; wave w owns q-rows qt..qt+15.
// Q pre-scaled by 1/sqrt(DK). K/V in [B,H,S,DK] bf16.
__global__ __launch_bounds__(256) void attn_kernel(const unsigned short* __restrict__ Qh,
    const unsigned short* __restrict__ Kh, const unsigned short* __restrict__ Vh,
    unsigned short* __restrict__ attnO)
{
  __shared__ __align__(16) unsigned short sVT[64*72];   // V^T tile, 72-padded rows
  __shared__ __align__(16) unsigned short sP[4*16*64];  // per-wave P tile (XOR-swizzled)
  const int tid = threadIdx.x;
  const int lane = tid & 63;
  const int w = tid >> 6;
  const int fr = lane & 15;
  const int kg = lane >> 4;
  const int bh = blockIdx.y;
  const int qt = blockIdx.x*64 + w*16;

  const unsigned short* Qb = Qh + ((size_t)bh*SEQ + qt)*DK;
  const unsigned short* Kb = Kh + (size_t)bh*SEQ*DK;
  const unsigned short* Vb = Vh + (size_t)bh*SEQ*DK;

  // Q A-frags: row fr, k = kg*8.. (+32 for second K-slice)
  bf16x8 qf0 = *(const bf16x8*)(Qb + fr*DK + kg*8);
  bf16x8 qf1 = *(const bf16x8*)(Qb + fr*DK + 32 + kg*8);

  f32x4 o[4];
  float mr[4], lr[4];
#pragma unroll
  for (int n = 0; n < 4; n++) o[n] = f32x4{0.f,0.f,0.f,0.f};
#pragma unroll
  for (int r = 0; r < 4; r++){ mr[r] = -1e30f; lr[r] = 0.f; }

  unsigned short* Pw = sP + w*(16*64);
  const int vk = tid & 63;
  const int vg = tid >> 6;

  for (int kt = 0; kt < SEQ; kt += 64){
    __syncthreads();
    // stage V^T tile: sVT[d][k] = V[kt+k][d]
#pragma unroll
    for (int half = 0; half < 2; half++){
      const int dg = half*4 + vg;
      us8 vv = *(const us8*)(Vb + (size_t)(kt + vk)*DK + dg*8);
#pragma unroll
      for (int i2 = 0; i2 < 8; i2++)
        sVT[(dg*8 + i2)*72 + vk] = vv[i2];
    }
    __syncthreads();

    // QK^T: 4 key-subtiles of 16, K-dim 64 = 2 MFMA slices
    f32x4 s[4];
#pragma unroll
    for (int n = 0; n < 4; n++){
      const unsigned short* kp = Kb + (size_t)(kt + n*16 + fr)*DK + kg*8;
      bf16x8 k0 = *(const bf16x8*)kp;
      bf16x8 k1 = *(const bf16x8*)(kp + 32);
      f32x4 z = f32x4{0.f,0.f,0.f,0.f};
      z    = __builtin_amdgcn_mfma_f32_16x16x32_bf16(qf0, k0, z, 0, 0, 0);
      s[n] = __builtin_amdgcn_mfma_f32_16x16x32_bf16(qf1, k1, z, 0, 0, 0);
    }

    // online softmax: row = kg*4 + r, cols spread over 16-lane groups
    float tm[4];
#pragma unroll
    for (int r = 0; r < 4; r++)
      tm[r] = fmaxf(fmaxf(s[0][r], s[1][r]), fmaxf(s[2][r], s[3][r]));
#pragma unroll
    for (int msk = 1; msk < 16; msk <<= 1){
#pragma unroll
      for (int r = 0; r < 4; r++) tm[r] = fmaxf(tm[r], __shfl_xor(tm[r], msk));
    }
    float al[4], rs[4];
#pragma unroll
    for (int r = 0; r < 4; r++){
      float mn = fmaxf(mr[r], tm[r]);
      al[r] = __expf(mr[r] - mn);
      mr[r] = mn;
      rs[r] = 0.f;
    }
#pragma unroll
    for (int n = 0; n < 4; n++){
#pragma unroll
      for (int r = 0; r < 4; r++){
        float p = __expf(s[n][r] - mr[r]);
        rs[r] += p;
        const int row  = kg*4 + r;
        const int colb = (n*32 + fr*2) ^ ((row & 7) << 4);  // XOR-swizzle (G4)
        *(unsigned short*)((char*)Pw + row*128 + colb) = f2bf(p);
      }
    }
#pragma unroll
    for (int msk = 1; msk < 16; msk <<= 1){
#pragma unroll
      for (int r = 0; r < 4; r++) rs[r] += __shfl_xor(rs[r], msk);
    }
    f32x4 alv;
#pragma unroll
    for (int r = 0; r < 4; r++){ lr[r] = lr[r]*al[r] + rs[r]; alv[r] = al[r]; }
#pragma unroll
    for (int n = 0; n < 4; n++) o[n] *= alv;

    // PV: A = P (LDS, swizzled), B = V^T tile (LDS)
    bf16x8 pf0 = *(const bf16x8*)((char*)Pw + fr*128 + (( 0 + kg*16) ^ ((fr & 7) << 4)));
    bf16x8 pf1 = *(const bf16x8*)((char*)Pw + fr*128 + ((64 + kg*16) ^ ((fr & 7) << 4)));
#pragma unroll
    for (int n = 0; n < 4; n++){
      const unsigned short* vtp = &sVT[(n*16 + fr)*72 + kg*8];
      bf16x8 v0 = *(const bf16x8*)vtp;
      bf16x8 v1 = *(const bf16x8*)(vtp + 32);
      o[n] = __builtin_amdgcn_mfma_f32_16x16x32_bf16(pf0, v0, o[n], 0, 0, 0);
      o[n] = __builtin_amdgcn_mfma_f32_16x16x32_bf16(pf1, v1, o[n], 0, 0, 0);
    }
  }

  // epilogue: attn[b, s, h*64+d] bf16, divide by (l + 1e-10) per reference
  const int b = bh >> 4, h = bh & (NH-1);
#pragma unroll
  for (int r = 0; r < 4; r++){
    const float inv = 1.f / (lr[r] + 1e-10f);
    const int srow = qt + kg*4 + r;
    const size_t base = ((size_t)b*SEQ + srow)*DMODEL + (size_t)h*DK;
#pragma unroll
    for (int n = 0; n < 4; n++)
      attnO[base + n*16 + fr] = f2bf(o[n][r] * inv);
  }
}

extern "C" void kernel_launch(void* const* d_in, const int* in_sizes, int n_in,
                              void* d_out, int out_size, void* d_ws, size_t ws_size,
                              hipStream_t stream)
{
  const float* q  = (const float*)d_in[0];
  const float* k  = (const float*)d_in[1];
  const float* v  = (const float*)d_in[2];
  const float* Wq = (const float*)d_in[3];
  const float* bq = (const float*)d_in[4];
  const float* Wk = (const float*)d_in[5];
  const float* bk = (const float*)d_in[6];
  const float* Wv = (const float*)d_in[7];
  const float* bv = (const float*)d_in[8];
  const float* Wo = (const float*)d_in[9];
  const float* bo = (const float*)d_in[10];

  char* ws = (char*)d_ws;
  const size_t WSZ = (size_t)DMODEL*DMODEL*2;   // 2 MB per weight (bf16)
  const size_t SZ  = (size_t)MTOT*DMODEL*2;     // 16 MB per token matrix (bf16)
  unsigned short* wqb   = (unsigned short*)(ws);
  unsigned short* wkb   = (unsigned short*)(ws + WSZ);
  unsigned short* wvb   = (unsigned short*)(ws + 2*WSZ);
  unsigned short* wob   = (unsigned short*)(ws + 3*WSZ);
  unsigned short* Qh    = (unsigned short*)(ws + 4*WSZ);
  unsigned short* Kh    = (unsigned short*)(ws + 4*WSZ + SZ);
  unsigned short* Vh    = (unsigned short*)(ws + 4*WSZ + 2*SZ);
  unsigned short* attnB = (unsigned short*)(ws + 4*WSZ + 3*SZ);

  const int n4 = DMODEL*DMODEL/4;
  cvt_kernel<<<n4/256, 256, 0, stream>>>(Wq, wqb, n4);
  cvt_kernel<<<n4/256, 256, 0, stream>>>(Wk, wkb, n4);
  cvt_kernel<<<n4/256, 256, 0, stream>>>(Wv, wvb, n4);
  cvt_kernel<<<n4/256, 256, 0, stream>>>(Wo, wob, n4);

  dim3 gproj(DMODEL/128, MTOT/128);   // (8, 64)
  gemm_bt<0,1><<<gproj, 256, 0, stream>>>(q, wqb, bq, Qh, 0.125f);  // Q, pre-scaled 1/sqrt(64)
  gemm_bt<0,1><<<gproj, 256, 0, stream>>>(k, wkb, bk, Kh, 1.0f);
  gemm_bt<0,1><<<gproj, 256, 0, stream>>>(v, wvb, bv, Vh, 1.0f);

  attn_kernel<<<dim3(SEQ/64, NB*NH), 256, 0, stream>>>(Qh, Kh, Vh, attnB);

  gemm_bt<2,0><<<gproj, 256, 0, stream>>>(attnB, wob, bo, d_out, 1.0f);
}